// Round 2
// baseline (21556.090 us; speedup 1.0000x reference)
//
#include <hip/hip_runtime.h>
#include <hip/hip_bf16.h>

// GatedMatchRNN: B=32, L1=128, L2=512, H=256
// Structure:
//   proj_kernel: y_proj = y@Wq^T + bq  -> ws (16MB f32)
//                x_up   = x@Wup^T + bup -> d_out (aliased scratch; overwritten
//                by the scan kernel AFTER it reads x_up[b,t,:] at step t)
//   scan_kernel: one block (1024 thr) per batch, full 128-step recurrence
//                in-block; only __syncthreads() needed.

#define B_ 32
#define L1_ 128
#define L2_ 512
#define H_ 256
#define LOG2E_ 1.4426950408889634f

__device__ __forceinline__ float fexp2(float x) {
#if __has_builtin(__builtin_amdgcn_exp2f)
  return __builtin_amdgcn_exp2f(x);
#else
  return exp2f(x);
#endif
}
__device__ __forceinline__ float frcp(float x) {
#if __has_builtin(__builtin_amdgcn_rcpf)
  return __builtin_amdgcn_rcpf(x);
#else
  return 1.0f / x;
#endif
}
// tanh(x) = 1 - 2/(1+exp(2x)); exp(2x)=exp2(x*2*log2(e)); saturates correctly.
__device__ __forceinline__ float ftanh(float x) {
  return 1.0f - 2.0f * frcp(1.0f + fexp2(x * (2.0f * LOG2E_)));
}
__device__ __forceinline__ float fsig(float x) {
  return frcp(1.0f + fexp2(-x * LOG2E_));
}
__device__ __forceinline__ float dot4(float4 a, float4 b) {
  return a.x * b.x + a.y * b.y + a.z * b.z + a.w * b.w;
}

// ---------------------------------------------------------------------------
// Projection kernel: blocks 0..511 -> y_proj, blocks 512..639 -> x_up.
// 640 blocks x 256 threads; each block: 32 rows x 256 outputs, K=256.
// A-rows staged in LDS (broadcast reads); W streamed per-thread (L2-hot).
// ---------------------------------------------------------------------------
__global__ __launch_bounds__(256) void proj_kernel(
    const float* __restrict__ y, const float* __restrict__ Wq,
    const float* __restrict__ bq, const float* __restrict__ x,
    const float* __restrict__ Wup, const float* __restrict__ bup,
    float* __restrict__ yp, float* __restrict__ xup) {
  __shared__ float As[32 * 256];
  const int blk = blockIdx.x;
  const int tid = threadIdx.x;
  const float* src;
  const float* W;
  const float* bias;
  float* dst;
  int row0;
  if (blk < 512) {  // y rows
    src = y; W = Wq; bias = bq; dst = yp; row0 = blk * 32;
  } else {          // x rows
    src = x; W = Wup; bias = bup; dst = xup; row0 = (blk - 512) * 32;
  }
  const float4* s4 = (const float4*)(src + (size_t)row0 * H_);
  float4* A4 = (float4*)As;
#pragma unroll
  for (int i = 0; i < 8; ++i) A4[i * 256 + tid] = s4[i * 256 + tid];
  __syncthreads();

  const float4* w4 = (const float4*)(W + (size_t)tid * H_);
  float acc[32];
#pragma unroll
  for (int r = 0; r < 32; ++r) acc[r] = 0.0f;
  for (int kc = 0; kc < 64; ++kc) {
    float4 w = w4[kc];
#pragma unroll
    for (int r = 0; r < 32; ++r) {
      float4 a = A4[r * 64 + kc];  // LDS broadcast (all lanes same addr)
      acc[r] += dot4(a, w);
    }
  }
  const float bb = bias[tid];
#pragma unroll 4
  for (int r = 0; r < 32; ++r)
    dst[(size_t)(row0 + r) * H_ + tid] = acc[r] + bb;  // coalesced
}

// ---------------------------------------------------------------------------
// Scan kernel: one block per batch, 1024 threads (16 waves).
// ---------------------------------------------------------------------------
__global__ __launch_bounds__(1024) void scan_kernel(
    const float* __restrict__ x, const int* __restrict__ x_mask,
    const float* __restrict__ y, const int* __restrict__ y_mask,
    const float* __restrict__ h0, const float* __restrict__ c0,
    const float* __restrict__ Wvp, const float* __restrict__ bvp,
    const float* __restrict__ Vw, const float* __restrict__ Vb,
    const float* __restrict__ Wg, const float* __restrict__ bg,
    const float* __restrict__ Wih, const float* __restrict__ Whh,
    const float* __restrict__ bih, const float* __restrict__ bhh,
    const float* __restrict__ yp, const float* __restrict__ xup,
    float* __restrict__ out) {
  const int b = blockIdx.x;
  const int tid = threadIdx.x;
  const int lane = tid & 63;
  const int wid = tid >> 6;

  __shared__ float h_s[H_], c_s[H_], q_s[H_], v_s[H_];
  __shared__ float pen_s[L2_];   // 0 or -inf (y_mask)
  __shared__ float e_s[L2_];     // scores, then exp(s-m)
  __shared__ float red_s[1024];  // partial-sum scratch
  __shared__ float mg_s[2 * H_]; // merge = [x_t, ct]
  __shared__ float li_s[2 * H_];
  __shared__ float gate_s[4 * H_];
  __shared__ float wred[16], wsum[16];

  const float NEG_INF = -__builtin_inff();

  if (tid < H_) {
    h_s[tid] = h0[b * H_ + tid];
    c_s[tid] = c0[b * H_ + tid];
    v_s[tid] = Vw[tid];
  }
  if (tid < L2_) pen_s[tid] = y_mask[b * L2_ + tid] ? NEG_INF : 0.0f;
  const float vb = Vb[0];
  __syncthreads();

  for (int t = 0; t < L1_; ++t) {
    const int xm = x_mask[b * L1_ + t];

    // ---- A: hid = h@Wvp^T + bvp ; q = hid + xup_t -------------------------
    {
      const int hh = tid & 255, part = tid >> 8;
      const float4* w4 = (const float4*)(Wvp + (size_t)hh * H_ + part * 64);
      const float4* h4 = (const float4*)(h_s + part * 64);
      float acc = 0.0f;
#pragma unroll
      for (int i = 0; i < 16; ++i) acc += dot4(w4[i], h4[i]);
      red_s[tid] = acc;
      __syncthreads();
      if (tid < H_) {
        float v = red_s[tid] + red_s[tid + 256] + red_s[tid + 512] +
                  red_s[tid + 768];
        q_s[tid] = v + bvp[tid] + xup[(size_t)(b * L1_ + t) * H_ + tid];
      }
      __syncthreads();
    }

    // ---- B: s[l] = Vb + sum_h v[h]*tanh(q[h]+yp[l,h])  (+mask) ------------
    {
      const int l = tid >> 1, half = tid & 1;
      const float4* yp4 =
          (const float4*)(yp + (size_t)(b * L2_ + l) * H_ + half * 128);
      const float4* q4 = (const float4*)(q_s + half * 128);
      const float4* v4 = (const float4*)(v_s + half * 128);
      float acc = 0.0f;
#pragma unroll 4
      for (int i = 0; i < 32; ++i) {
        float4 a = yp4[i], q = q4[i], vv = v4[i];
        acc += vv.x * ftanh(a.x + q.x) + vv.y * ftanh(a.y + q.y) +
               vv.z * ftanh(a.z + q.z) + vv.w * ftanh(a.w + q.w);
      }
      acc += __shfl_xor(acc, 1);
      if (half == 0) e_s[l] = acc + vb + pen_s[l];
      __syncthreads();
    }

    // ---- C: softmax stats (max, sum) over 512 -----------------------------
    float rsum;
    {
      float vmax = (tid < L2_) ? e_s[tid] : NEG_INF;
#pragma unroll
      for (int off = 32; off >= 1; off >>= 1)
        vmax = fmaxf(vmax, __shfl_xor(vmax, off));
      if (lane == 0) wred[wid] = vmax;
      __syncthreads();
      float m = wred[0];
#pragma unroll
      for (int i = 1; i < 16; ++i) m = fmaxf(m, wred[i]);
      float e = 0.0f;
      if (tid < L2_) {
        e = fexp2((e_s[tid] - m) * LOG2E_);  // masked -> exp2(-inf)=0
        e_s[tid] = e;
      }
      float ssum = e;
#pragma unroll
      for (int off = 32; off >= 1; off >>= 1) ssum += __shfl_xor(ssum, off);
      if (lane == 0) wsum[wid] = ssum;
      __syncthreads();
      float tot = 0.0f;
#pragma unroll
      for (int i = 0; i < 16; ++i) tot += wsum[i];
      rsum = frcp(tot);
    }

    // ---- D: ct = (e@y)*rsum ; merge=[x_t, ct] -----------------------------
    {
      const int d = tid & 255, part = tid >> 8;
      const float* yb = y + (size_t)(b * L2_ + part * 128) * H_ + d;
      float acc = 0.0f;
#pragma unroll 8
      for (int l = 0; l < 128; ++l)
        acc += e_s[part * 128 + l] * yb[(size_t)l * H_];  // coalesced in d
      __syncthreads();  // protect red_s (previous readers done anyway)
      red_s[tid] = acc;
      __syncthreads();
      if (tid < H_) {
        float ct = (red_s[tid] + red_s[tid + 256] + red_s[tid + 512] +
                    red_s[tid + 768]) * rsum;
        mg_s[tid] = x[(size_t)(b * L1_ + t) * H_ + tid];
        mg_s[H_ + tid] = ct;
      }
      __syncthreads();
    }

    // ---- E: gt = sigmoid(merge@Wg^T + bg); li = mask?0:gt*merge -----------
    {
      const int k = tid >> 1, half = tid & 1;
      const float4* wg4 =
          (const float4*)(Wg + (size_t)k * 512 + half * 256);
      const float4* m4 = (const float4*)(mg_s + half * 256);
      float acc = 0.0f;
#pragma unroll 8
      for (int i = 0; i < 64; ++i) acc += dot4(wg4[i], m4[i]);
      acc += __shfl_xor(acc, 1);
      if (half == 0) {
        float g = fsig(acc + bg[k]);
        li_s[k] = xm ? 0.0f : g * mg_s[k];
      }
      __syncthreads();
    }

    // ---- F: gates = li@Wih^T + bih + h@Whh^T + bhh; LSTM pointwise --------
    {
      const float4* wi4 = (const float4*)(Wih + (size_t)tid * 512);
      const float4* l4p = (const float4*)li_s;
      float acc = bih[tid] + bhh[tid];
#pragma unroll 8
      for (int i = 0; i < 128; ++i) acc += dot4(wi4[i], l4p[i]);
      const float4* wh4 = (const float4*)(Whh + (size_t)tid * 256);
      const float4* h4 = (const float4*)h_s;
#pragma unroll 8
      for (int i = 0; i < 64; ++i) acc += dot4(wh4[i], h4[i]);
      gate_s[tid] = acc;
      __syncthreads();
      if (tid < H_) {
        float ig = fsig(gate_s[tid]);
        float fg = fsig(gate_s[H_ + tid]);
        float gg = ftanh(gate_s[2 * H_ + tid]);
        float og = fsig(gate_s[3 * H_ + tid]);
        float cn = fg * c_s[tid] + ig * gg;
        float hn = og * ftanh(cn);
        hn = xm ? 0.0f : hn;
        c_s[tid] = cn;
        h_s[tid] = hn;
        out[(size_t)(b * L1_ + t) * H_ + tid] = hn;  // overwrites xup[b,t,:]
      }
      __syncthreads();
    }
  }
}

extern "C" void kernel_launch(void* const* d_in, const int* in_sizes, int n_in,
                              void* d_out, int out_size, void* d_ws,
                              size_t ws_size, hipStream_t stream) {
  const float* x = (const float*)d_in[0];
  const int* x_mask = (const int*)d_in[1];
  const float* y = (const float*)d_in[2];
  const int* y_mask = (const int*)d_in[3];
  const float* h0 = (const float*)d_in[4];
  const float* c0 = (const float*)d_in[5];
  const float* Wq = (const float*)d_in[6];
  const float* bq = (const float*)d_in[7];
  const float* Wup = (const float*)d_in[8];
  const float* bup = (const float*)d_in[9];
  const float* Wvp = (const float*)d_in[10];
  const float* bvp = (const float*)d_in[11];
  const float* Vw = (const float*)d_in[12];
  const float* Vb = (const float*)d_in[13];
  const float* Wg = (const float*)d_in[14];
  const float* bg = (const float*)d_in[15];
  const float* Wih = (const float*)d_in[16];
  const float* Whh = (const float*)d_in[17];
  const float* bih = (const float*)d_in[18];
  const float* bhh = (const float*)d_in[19];

  float* out = (float*)d_out;
  float* yp = (float*)d_ws;  // 32*512*256 f32 = 16 MB
  float* xup = out;          // x_up aliased into d_out (safe; see scan order)

  proj_kernel<<<dim3(640), dim3(256), 0, stream>>>(y, Wq, bq, x, Wup, bup, yp,
                                                   xup);
  scan_kernel<<<dim3(B_), dim3(1024), 0, stream>>>(
      x, x_mask, y, y_mask, h0, c0, Wvp, bvp, Vw, Vb, Wg, bg, Wih, Whh, bih,
      bhh, yp, xup, out);
}

// Round 3
// 18022.765 us; speedup vs baseline: 1.1960x; 1.1960x over previous
//
#include <hip/hip_runtime.h>
#include <hip/hip_bf16.h>

// GatedMatchRNN: B=32, L1=128, L2=512, H=256
// Round 3: 8 blocks per batch (256 blocks x 512 thr), slice-owned weights,
// device-scope group barriers, bf16 yp/xup, softmax without global max.

#define B_ 32
#define L1_ 128
#define L2_ 512
#define H_ 256
#define GRP 8
#define TB 512
#define LOG2E_ 1.4426950408889634f

// ws layout (bytes); total ~10.7 MB (ws >= 16 MB proven by round 2)
#define YP_OFF   0u                        // bf16 [32][512][256] = 8 MB
#define XUP_OFF  (8u << 20)                // bf16 [32][128][256] = 2 MB
#define QP_OFF   (10u << 20)               // f32 [32][8][256] = 256 KB
#define CTP_OFF  (QP_OFF + (256u << 10))   // f32 [32][8][256] = 256 KB
#define ES_OFF   (CTP_OFF + (256u << 10))  // f32 [32][8] (padded 4 KB)
#define LI_OFF   (ES_OFF + (4u << 10))     // f32 [32][512] = 64 KB
#define HB_OFF   (LI_OFF + (64u << 10))    // f32 [32][256] = 32 KB
#define BAR_OFF  (HB_OFF + (32u << 10))    // uint [32][32] = 4 KB

__device__ __forceinline__ float fexp2(float x) {
#if __has_builtin(__builtin_amdgcn_exp2f)
  return __builtin_amdgcn_exp2f(x);
#else
  return exp2f(x);
#endif
}
__device__ __forceinline__ float frcp(float x) {
#if __has_builtin(__builtin_amdgcn_rcpf)
  return __builtin_amdgcn_rcpf(x);
#else
  return 1.0f / x;
#endif
}
__device__ __forceinline__ float ftanh(float x) {
  return 1.0f - 2.0f * frcp(1.0f + fexp2(x * (2.0f * LOG2E_)));
}
__device__ __forceinline__ float fsig(float x) {
  return frcp(1.0f + fexp2(-x * LOG2E_));
}
__device__ __forceinline__ float dot4(float4 a, float4 b) {
  return a.x * b.x + a.y * b.y + a.z * b.z + a.w * b.w;
}
// bf16 (low/high half of a u32) -> f32, exact
__device__ __forceinline__ float bfl(unsigned u) {
  return __uint_as_float(u << 16);
}
__device__ __forceinline__ float bfh(unsigned u) {
  return __uint_as_float(u & 0xffff0000u);
}

// Device-scope generation barrier among GRP blocks of one batch.
__device__ __forceinline__ void group_barrier(unsigned* cnt, unsigned* gen,
                                              unsigned target) {
  __syncthreads();
  if (threadIdx.x == 0) {
    __threadfence();  // release prior writes (agent scope)
    unsigned prev = atomicAdd(cnt, 1u);
    if (prev == GRP - 1) {
      atomicExch(cnt, 0u);
      __threadfence();
      atomicAdd(gen, 1u);
    } else {
      while (__hip_atomic_load(gen, __ATOMIC_ACQUIRE,
                               __HIP_MEMORY_SCOPE_AGENT) < target) {
        __builtin_amdgcn_s_sleep(2);
      }
    }
  }
  __syncthreads();
  __threadfence();  // acquire: invalidate L1 so remote writes are visible
}

// ---------------------------------------------------------------------------
// Projection: blocks 0..511 -> yp (bf16), 512..639 -> xup (bf16).
// ---------------------------------------------------------------------------
__global__ __launch_bounds__(256) void proj_kernel(
    const float* __restrict__ y, const float* __restrict__ Wq,
    const float* __restrict__ bq, const float* __restrict__ x,
    const float* __restrict__ Wup, const float* __restrict__ bup,
    __hip_bfloat16* __restrict__ yp, __hip_bfloat16* __restrict__ xup) {
  __shared__ float As[32 * 256];
  const int blk = blockIdx.x;
  const int tid = threadIdx.x;
  const float* src;
  const float* W;
  const float* bias;
  __hip_bfloat16* dst;
  int row0;
  if (blk < 512) {
    src = y; W = Wq; bias = bq; dst = yp; row0 = blk * 32;
  } else {
    src = x; W = Wup; bias = bup; dst = xup; row0 = (blk - 512) * 32;
  }
  const float4* s4 = (const float4*)(src + (size_t)row0 * H_);
  float4* A4 = (float4*)As;
#pragma unroll
  for (int i = 0; i < 8; ++i) A4[i * 256 + tid] = s4[i * 256 + tid];
  __syncthreads();

  const float4* w4 = (const float4*)(W + (size_t)tid * H_);
  float acc[32];
#pragma unroll
  for (int r = 0; r < 32; ++r) acc[r] = 0.0f;
  for (int kc = 0; kc < 64; ++kc) {
    float4 w = w4[kc];
#pragma unroll
    for (int r = 0; r < 32; ++r) acc[r] += dot4(A4[r * 64 + kc], w);
  }
  const float bb = bias[tid];
#pragma unroll 4
  for (int r = 0; r < 32; ++r)
    dst[(size_t)(row0 + r) * H_ + tid] = __float2bfloat16(acc[r] + bb);
}

// ---------------------------------------------------------------------------
// Scan: block (b,g) = blockIdx (b = blk>>3, g = blk&7). 512 threads.
// ---------------------------------------------------------------------------
__global__ __launch_bounds__(TB) void scan_kernel(
    const float* __restrict__ x, const int* __restrict__ x_mask,
    const float* __restrict__ y, const int* __restrict__ y_mask,
    const float* __restrict__ h0, const float* __restrict__ c0,
    const float* __restrict__ Wvp, const float* __restrict__ bvp,
    const float* __restrict__ Vw, const float* __restrict__ Vb,
    const float* __restrict__ Wg, const float* __restrict__ bg,
    const float* __restrict__ Wih, const float* __restrict__ Whh,
    const float* __restrict__ bih, const float* __restrict__ bhh,
    char* __restrict__ ws, float* __restrict__ out) {
  const int blk = blockIdx.x;
  const int b = blk >> 3;
  const int g = blk & 7;  // same-g blocks land on the same XCD (round-robin)
  const int tid = threadIdx.x;

  const __hip_bfloat16* yp = (const __hip_bfloat16*)(ws + YP_OFF);
  const __hip_bfloat16* xup = (const __hip_bfloat16*)(ws + XUP_OFF);
  float* qp = (float*)(ws + QP_OFF);
  float* ctp = (float*)(ws + CTP_OFF);
  float* esb = (float*)(ws + ES_OFF);
  float* lib = (float*)(ws + LI_OFF);
  float* hb = (float*)(ws + HB_OFF);
  unsigned* bar = (unsigned*)(ws + BAR_OFF);
  unsigned* cnt = bar + b * 32;
  unsigned* gen = bar + b * 32 + 16;

  __shared__ __align__(16) float h_s[H_];
  __shared__ float q_s[H_];
  __shared__ float v_s[H_];
  __shared__ float e_s[64];
  __shared__ __align__(16) float mg_s[2 * H_];
  __shared__ __align__(16) float li_s[2 * H_];
  __shared__ float gate_s[128];
  __shared__ float red_s[64 * 9];
  __shared__ float esum_s[8];
  __shared__ __align__(16) float c_s[32];
  __shared__ __align__(16) float hn_s[32];
  __shared__ int ym_s[64];

  unsigned target = 0;

  // ---- init ----
  if (tid < H_) v_s[tid] = Vw[tid];
  if (tid < 64) ym_s[tid] = y_mask[b * L2_ + g * 64 + tid];
  if (tid < 32) {
    float hv = h0[b * H_ + g * 32 + tid];
    c_s[tid] = c0[b * H_ + g * 32 + tid];
    hn_s[tid] = hv;
    hb[b * H_ + g * 32 + tid] = hv;
  }
  const float vb = Vb[0];
  __syncthreads();
  {  // A': qpart from h0 slice (column-split of Wvp)
    const int j = tid >> 1, sub = tid & 1;
    const float4* w4 = (const float4*)(Wvp + (size_t)j * H_ + g * 32 + sub * 16);
    const float4* hv4 = (const float4*)(hn_s + sub * 16);
    float acc = 0.f;
#pragma unroll
    for (int i = 0; i < 4; ++i) acc += dot4(w4[i], hv4[i]);
    acc += __shfl_xor(acc, 1);
    if (sub == 0) qp[(b * 8 + g) * H_ + j] = acc;
  }
  group_barrier(cnt, gen, ++target);

  for (int t = 0; t < L1_; ++t) {
    const int xm = x_mask[b * L1_ + t];

    // ---- q finalize + load prev h ----
    if (tid < H_) {
      h_s[tid] = hb[b * H_ + tid];
      float acc = bvp[tid] + bfl(((const unsigned short*)xup)[(size_t)(b * L1_ + t) * H_ + tid]);
#pragma unroll
      for (int g2 = 0; g2 < 8; ++g2) acc += qp[(b * 8 + g2) * H_ + tid];
      q_s[tid] = acc;
    }
    __syncthreads();

    // ---- B: scores for l-slice [g*64, g*64+64) ----
    {
      const int l = tid & 63, sub = tid >> 6;  // sub wave-uniform -> LDS bcast
      const uint4* yp4 =
          (const uint4*)(yp + (size_t)(b * L2_ + g * 64 + l) * H_ + sub * 32);
      float acc = 0.f;
#pragma unroll
      for (int i = 0; i < 4; ++i) {
        uint4 u = yp4[i];
        const int h = sub * 32 + i * 8;
        acc += v_s[h + 0] * ftanh(q_s[h + 0] + bfl(u.x));
        acc += v_s[h + 1] * ftanh(q_s[h + 1] + bfh(u.x));
        acc += v_s[h + 2] * ftanh(q_s[h + 2] + bfl(u.y));
        acc += v_s[h + 3] * ftanh(q_s[h + 3] + bfh(u.y));
        acc += v_s[h + 4] * ftanh(q_s[h + 4] + bfl(u.z));
        acc += v_s[h + 5] * ftanh(q_s[h + 5] + bfh(u.z));
        acc += v_s[h + 6] * ftanh(q_s[h + 6] + bfl(u.w));
        acc += v_s[h + 7] * ftanh(q_s[h + 7] + bfh(u.w));
      }
      red_s[l * 9 + sub] = acc;  // stride 9: conflict-free (2-way is free)
    }
    __syncthreads();
    if (tid < 64) {
      float s = vb;
#pragma unroll
      for (int k = 0; k < 8; ++k) s += red_s[tid * 9 + k];
      // |s| <= |Vb| + sum|v| ~ 13  -> exp2 never overflows; no max needed
      float e = ym_s[tid] ? 0.f : fexp2(s * LOG2E_);
      e_s[tid] = e;
      float ss = e;
#pragma unroll
      for (int off = 32; off >= 1; off >>= 1) ss += __shfl_xor(ss, off);
      if (tid == 0) esb[b * 8 + g] = ss;
    }
    __syncthreads();

    // ---- ct partial over the l-slice ----
    {
      const int d = tid & 255, part = tid >> 8;
      const float* yb = y + (size_t)(b * L2_ + g * 64 + part * 32) * H_ + d;
      float acc = 0.f;
#pragma unroll 8
      for (int i = 0; i < 32; ++i)
        acc += e_s[part * 32 + i] * yb[(size_t)i * H_];
      red_s[tid] = acc;
    }
    __syncthreads();
    if (tid < H_) ctp[(b * 8 + g) * H_ + tid] = red_s[tid] + red_s[tid + 256];
    group_barrier(cnt, gen, ++target);

    // ---- ct finalize + merge ----
    if (tid < 8) esum_s[tid] = esb[b * 8 + tid];
    if (tid < H_) mg_s[tid] = x[(size_t)(b * L1_ + t) * H_ + tid];
    __syncthreads();
    if (tid < H_) {
      float tot = esum_s[0] + esum_s[1] + esum_s[2] + esum_s[3] + esum_s[4] +
                  esum_s[5] + esum_s[6] + esum_s[7];
      float ctv = 0.f;
#pragma unroll
      for (int g2 = 0; g2 < 8; ++g2) ctv += ctp[(b * 8 + g2) * H_ + tid];
      mg_s[H_ + tid] = ctv * frcp(tot);
    }
    __syncthreads();

    // ---- E: li-slice [g*64, g*64+64) ----
    {
      const int o = tid >> 3, sub = tid & 7;
      const float4* wg4 = (const float4*)(Wg + (size_t)(g * 64 + o) * 512);
      const float4* m4 = (const float4*)mg_s;
      float acc = 0.f;
#pragma unroll
      for (int j = 0; j < 16; ++j)
        acc += dot4(wg4[sub + 8 * j], m4[sub + 8 * j]);
      acc += __shfl_xor(acc, 1);
      acc += __shfl_xor(acc, 2);
      acc += __shfl_xor(acc, 4);
      if (sub == 0) {
        float gt = fsig(acc + bg[g * 64 + o]);
        lib[b * 512 + g * 64 + o] = xm ? 0.f : gt * mg_s[g * 64 + o];
      }
    }
    group_barrier(cnt, gen, ++target);

    // ---- F: gates for h-dims [g*32, g*32+32) ----
    li_s[tid] = lib[b * 512 + tid];
    __syncthreads();
    {
      const int r = tid >> 2, sub = tid & 3;
      const int grow = (r >> 5) * H_ + g * 32 + (r & 31);
      const float4* wi4 = (const float4*)(Wih + (size_t)grow * 512);
      const float4* wh4 = (const float4*)(Whh + (size_t)grow * 256);
      const float4* l4 = (const float4*)li_s;
      const float4* h4 = (const float4*)h_s;
      float acc = 0.f;
#pragma unroll 8
      for (int j = 0; j < 32; ++j) acc += dot4(wi4[sub + 4 * j], l4[sub + 4 * j]);
#pragma unroll 8
      for (int j = 0; j < 16; ++j) acc += dot4(wh4[sub + 4 * j], h4[sub + 4 * j]);
      acc += __shfl_xor(acc, 1);
      acc += __shfl_xor(acc, 2);
      if (sub == 0) gate_s[r] = acc + bih[grow] + bhh[grow];
    }
    __syncthreads();
    if (tid < 32) {
      float ii = gate_s[tid], ff = gate_s[32 + tid];
      float gg = gate_s[64 + tid], oo = gate_s[96 + tid];
      float cn = fsig(ff) * c_s[tid] + fsig(ii) * ftanh(gg);
      float hn = xm ? 0.f : fsig(oo) * ftanh(cn);
      c_s[tid] = cn;
      hn_s[tid] = hn;
      hb[b * H_ + g * 32 + tid] = hn;
      out[(size_t)(b * L1_ + t) * H_ + g * 32 + tid] = hn;
    }
    __syncthreads();

    // ---- A': qpart for next step from new h slice ----
    {
      const int j = tid >> 1, sub = tid & 1;
      const float4* w4 = (const float4*)(Wvp + (size_t)j * H_ + g * 32 + sub * 16);
      const float4* hv4 = (const float4*)(hn_s + sub * 16);
      float acc = 0.f;
#pragma unroll
      for (int i = 0; i < 4; ++i) acc += dot4(w4[i], hv4[i]);
      acc += __shfl_xor(acc, 1);
      if (sub == 0) qp[(b * 8 + g) * H_ + j] = acc;
    }
    group_barrier(cnt, gen, ++target);
  }
}

extern "C" void kernel_launch(void* const* d_in, const int* in_sizes, int n_in,
                              void* d_out, int out_size, void* d_ws,
                              size_t ws_size, hipStream_t stream) {
  const float* x = (const float*)d_in[0];
  const int* x_mask = (const int*)d_in[1];
  const float* y = (const float*)d_in[2];
  const int* y_mask = (const int*)d_in[3];
  const float* h0 = (const float*)d_in[4];
  const float* c0 = (const float*)d_in[5];
  const float* Wq = (const float*)d_in[6];
  const float* bq = (const float*)d_in[7];
  const float* Wup = (const float*)d_in[8];
  const float* bup = (const float*)d_in[9];
  const float* Wvp = (const float*)d_in[10];
  const float* bvp = (const float*)d_in[11];
  const float* Vw = (const float*)d_in[12];
  const float* Vb = (const float*)d_in[13];
  const float* Wg = (const float*)d_in[14];
  const float* bg = (const float*)d_in[15];
  const float* Wih = (const float*)d_in[16];
  const float* Whh = (const float*)d_in[17];
  const float* bih = (const float*)d_in[18];
  const float* bhh = (const float*)d_in[19];

  float* out = (float*)d_out;
  char* ws = (char*)d_ws;

  hipMemsetAsync(ws + BAR_OFF, 0, 4096, stream);  // barrier state (re-poisoned)
  proj_kernel<<<dim3(640), dim3(256), 0, stream>>>(
      y, Wq, bq, x, Wup, bup, (__hip_bfloat16*)(ws + YP_OFF),
      (__hip_bfloat16*)(ws + XUP_OFF));
  scan_kernel<<<dim3(B_ * GRP), dim3(TB), 0, stream>>>(
      x, x_mask, y, y_mask, h0, c0, Wvp, bvp, Vw, Vb, Wg, bg, Wih, Whh, bih,
      bhh, ws, out);
}

// Round 4
// 1773.559 us; speedup vs baseline: 12.1541x; 10.1619x over previous
//
#include <hip/hip_runtime.h>
#include <hip/hip_bf16.h>

// GatedMatchRNN: B=32, L1=128, L2=512, H=256
// Round 4: fence-free cross-block comm via per-access device-scope relaxed
// atomics (no L2-invalidating __threadfence), t-invariant yp/y slices staged
// in LDS (yp XOR-swizzled). Weights stay L2-resident across all 128 steps.

#define B_ 32
#define L1_ 128
#define L2_ 512
#define H_ 256
#define GRP 8
#define TB 512
#define LOG2E_ 1.4426950408889634f

// ws layout (bytes)
#define YP_OFF   0u                        // bf16 [32][512][256] = 8 MB
#define XUP_OFF  (8u << 20)                // bf16 [32][128][256] = 2 MB
#define QP_OFF   (10u << 20)               // f32 [32][8][256] = 256 KB
#define CTP_OFF  (QP_OFF + (256u << 10))   // f32 [32][8][256] = 256 KB
#define ES_OFF   (CTP_OFF + (256u << 10))  // f32 [32][8] (padded 4 KB)
#define LI_OFF   (ES_OFF + (4u << 10))     // f32 [32][512] = 64 KB
#define HB_OFF   (LI_OFF + (64u << 10))    // f32 [32][256] = 32 KB
#define BAR_OFF  (HB_OFF + (32u << 10))    // uint [32][32] = 4 KB

__device__ __forceinline__ float fexp2(float x) {
#if __has_builtin(__builtin_amdgcn_exp2f)
  return __builtin_amdgcn_exp2f(x);
#else
  return exp2f(x);
#endif
}
__device__ __forceinline__ float frcp(float x) {
#if __has_builtin(__builtin_amdgcn_rcpf)
  return __builtin_amdgcn_rcpf(x);
#else
  return 1.0f / x;
#endif
}
__device__ __forceinline__ float ftanh(float x) {
  return 1.0f - 2.0f * frcp(1.0f + fexp2(x * (2.0f * LOG2E_)));
}
__device__ __forceinline__ float fsig(float x) {
  return frcp(1.0f + fexp2(-x * LOG2E_));
}
__device__ __forceinline__ float dot4(float4 a, float4 b) {
  return a.x * b.x + a.y * b.y + a.z * b.z + a.w * b.w;
}
__device__ __forceinline__ float bfl(unsigned u) {
  return __uint_as_float(u << 16);
}
__device__ __forceinline__ float bfh(unsigned u) {
  return __uint_as_float(u & 0xffff0000u);
}

// Per-access device-coherent load/store (sc0 sc1; bypass L1, force-miss L2).
// No cache-wide invalidates -> weight lines stay hot in L2.
__device__ __forceinline__ float cload(const float* p) {
  return __hip_atomic_load(p, __ATOMIC_RELAXED, __HIP_MEMORY_SCOPE_AGENT);
}
__device__ __forceinline__ void cstore(float* p, float v) {
  __hip_atomic_store(p, v, __ATOMIC_RELAXED, __HIP_MEMORY_SCOPE_AGENT);
}

// Monotonic-counter group barrier (GRP blocks of one batch). Release is
// physical: vmcnt(0) drains all prior coherent (write-through) stores before
// the arrive-add becomes visible. Spin uses an RMW read (always coherent).
__device__ __forceinline__ void group_barrier(unsigned* cnt, unsigned target) {
  __syncthreads();
  if (threadIdx.x == 0) {
    asm volatile("s_waitcnt vmcnt(0)" ::: "memory");
    __hip_atomic_fetch_add(cnt, 1u, __ATOMIC_RELAXED,
                           __HIP_MEMORY_SCOPE_AGENT);
    while (__hip_atomic_fetch_add(cnt, 0u, __ATOMIC_RELAXED,
                                  __HIP_MEMORY_SCOPE_AGENT) <
           GRP * target) {
    }
  }
  __syncthreads();
  asm volatile("" ::: "memory");  // no compile-time reorder of data loads up
}

// ---------------------------------------------------------------------------
// Projection: blocks 0..511 -> yp (bf16), 512..639 -> xup (bf16).
// ---------------------------------------------------------------------------
__global__ __launch_bounds__(256) void proj_kernel(
    const float* __restrict__ y, const float* __restrict__ Wq,
    const float* __restrict__ bq, const float* __restrict__ x,
    const float* __restrict__ Wup, const float* __restrict__ bup,
    __hip_bfloat16* __restrict__ yp, __hip_bfloat16* __restrict__ xup) {
  __shared__ float As[32 * 256];
  const int blk = blockIdx.x;
  const int tid = threadIdx.x;
  const float* src;
  const float* W;
  const float* bias;
  __hip_bfloat16* dst;
  int row0;
  if (blk < 512) {
    src = y; W = Wq; bias = bq; dst = yp; row0 = blk * 32;
  } else {
    src = x; W = Wup; bias = bup; dst = xup; row0 = (blk - 512) * 32;
  }
  const float4* s4 = (const float4*)(src + (size_t)row0 * H_);
  float4* A4 = (float4*)As;
#pragma unroll
  for (int i = 0; i < 8; ++i) A4[i * 256 + tid] = s4[i * 256 + tid];
  __syncthreads();

  const float4* w4 = (const float4*)(W + (size_t)tid * H_);
  float acc[32];
#pragma unroll
  for (int r = 0; r < 32; ++r) acc[r] = 0.0f;
  for (int kc = 0; kc < 64; ++kc) {
    float4 w = w4[kc];
#pragma unroll
    for (int r = 0; r < 32; ++r) acc[r] += dot4(A4[r * 64 + kc], w);
  }
  const float bb = bias[tid];
#pragma unroll 4
  for (int r = 0; r < 32; ++r)
    dst[(size_t)(row0 + r) * H_ + tid] = __float2bfloat16(acc[r] + bb);
}

// ---------------------------------------------------------------------------
// Scan: block (b,g); b = blk>>3, g = blk&7. 512 threads.
// ---------------------------------------------------------------------------
__global__ __launch_bounds__(TB) void scan_kernel(
    const float* __restrict__ x, const int* __restrict__ x_mask,
    const float* __restrict__ y, const int* __restrict__ y_mask,
    const float* __restrict__ h0, const float* __restrict__ c0,
    const float* __restrict__ Wvp, const float* __restrict__ bvp,
    const float* __restrict__ Vw, const float* __restrict__ Vb,
    const float* __restrict__ Wg, const float* __restrict__ bg,
    const float* __restrict__ Wih, const float* __restrict__ Whh,
    const float* __restrict__ bih, const float* __restrict__ bhh,
    char* __restrict__ ws, float* __restrict__ out) {
  const int blk = blockIdx.x;
  const int b = blk >> 3;
  const int g = blk & 7;  // same-g blocks share an XCD L2 (perf heuristic only)
  const int tid = threadIdx.x;

  const __hip_bfloat16* yp = (const __hip_bfloat16*)(ws + YP_OFF);
  const unsigned short* xupb = (const unsigned short*)(ws + XUP_OFF);
  float* qp = (float*)(ws + QP_OFF);
  float* ctp = (float*)(ws + CTP_OFF);
  float* esb = (float*)(ws + ES_OFF);
  float* lib = (float*)(ws + LI_OFF);
  float* hb = (float*)(ws + HB_OFF);
  unsigned* cnt = (unsigned*)(ws + BAR_OFF) + b * 32;  // 128B apart per batch

  __shared__ uint4 yp_lds[64 * 32];  // 32 KB, XOR-swizzled bf16 rows
  __shared__ float y_lds[64 * 256];  // 64 KB
  __shared__ __align__(16) float h_s[H_];
  __shared__ float q_s[H_];
  __shared__ float v_s[H_];
  __shared__ float e_s[64];
  __shared__ __align__(16) float mg_s[2 * H_];
  __shared__ __align__(16) float li_s[2 * H_];
  __shared__ float gate_s[128];
  __shared__ float red_s[64 * 9];
  __shared__ float esum_s[8];
  __shared__ __align__(16) float c_s[32];
  __shared__ __align__(16) float hn_s[32];
  __shared__ int ym_s[64];

  unsigned target = 0;

  // ---- stage t-invariant slices ----
  {
    const __hip_bfloat16* yprow = yp + (size_t)(b * L2_ + g * 64) * H_;
    const uint4* src = (const uint4*)yprow;  // 64 rows x 32 chunks of 16B
    for (int k = tid; k < 64 * 32; k += TB) {
      int r = k >> 5, c = k & 31;
      yp_lds[r * 32 + (c ^ (r & 31))] = src[k];  // swizzle: kill 32-way bank hit
    }
    const float4* ys = (const float4*)(y + (size_t)(b * L2_ + g * 64) * H_);
    float4* yd = (float4*)y_lds;
    for (int k = tid; k < 64 * 64; k += TB) yd[k] = ys[k];
  }
  if (tid < H_) v_s[tid] = Vw[tid];
  if (tid < 64) ym_s[tid] = y_mask[b * L2_ + g * 64 + tid];
  if (tid < 32) {
    float hv = h0[b * H_ + g * 32 + tid];
    c_s[tid] = c0[b * H_ + g * 32 + tid];
    hn_s[tid] = hv;
    cstore(&hb[b * H_ + g * 32 + tid], hv);
  }
  const float vb = Vb[0];
  __syncthreads();
  {  // initial qpart from h0 slice (column-split of Wvp)
    const int j = tid >> 1, sub = tid & 1;
    const float4* w4 =
        (const float4*)(Wvp + (size_t)j * H_ + g * 32 + sub * 16);
    const float4* hv4 = (const float4*)(hn_s + sub * 16);
    float acc = 0.f;
#pragma unroll
    for (int i = 0; i < 4; ++i) acc += dot4(w4[i], hv4[i]);
    acc += __shfl_xor(acc, 1);
    if (sub == 0) cstore(&qp[(b * 8 + g) * H_ + j], acc);
  }
  group_barrier(cnt, ++target);

  for (int t = 0; t < L1_; ++t) {
    const int xm = x_mask[b * L1_ + t];

    // ---- q finalize + load prev h (coherent reads) ------------------------
    if (tid < H_) {
      h_s[tid] = cload(&hb[b * H_ + tid]);
      float acc = bvp[tid] + bfl(xupb[(size_t)(b * L1_ + t) * H_ + tid]);
#pragma unroll
      for (int g2 = 0; g2 < 8; ++g2) acc += cload(&qp[(b * 8 + g2) * H_ + tid]);
      q_s[tid] = acc;
    }
    __syncthreads();

    // ---- B: scores for l-slice [g*64, g*64+64), yp from swizzled LDS ------
    {
      const int l = tid & 63, sub = tid >> 6;
      float acc = 0.f;
#pragma unroll
      for (int i = 0; i < 4; ++i) {
        uint4 u = yp_lds[l * 32 + ((sub * 4 + i) ^ (l & 31))];
        const int h = sub * 32 + i * 8;
        acc += v_s[h + 0] * ftanh(q_s[h + 0] + bfl(u.x));
        acc += v_s[h + 1] * ftanh(q_s[h + 1] + bfh(u.x));
        acc += v_s[h + 2] * ftanh(q_s[h + 2] + bfl(u.y));
        acc += v_s[h + 3] * ftanh(q_s[h + 3] + bfh(u.y));
        acc += v_s[h + 4] * ftanh(q_s[h + 4] + bfl(u.z));
        acc += v_s[h + 5] * ftanh(q_s[h + 5] + bfh(u.z));
        acc += v_s[h + 6] * ftanh(q_s[h + 6] + bfl(u.w));
        acc += v_s[h + 7] * ftanh(q_s[h + 7] + bfh(u.w));
      }
      red_s[l * 9 + sub] = acc;  // stride 9 (2-way max, free)
    }
    __syncthreads();
    if (tid < 64) {
      float s = vb;
#pragma unroll
      for (int k = 0; k < 8; ++k) s += red_s[tid * 9 + k];
      // |s| <= |Vb| + sum|v| ~ 13 -> exp never overflows; no global max
      float e = ym_s[tid] ? 0.f : fexp2(s * LOG2E_);
      e_s[tid] = e;
      float ss = e;
#pragma unroll
      for (int off = 32; off >= 1; off >>= 1) ss += __shfl_xor(ss, off);
      if (tid == 0) cstore(&esb[b * 8 + g], ss);
    }
    __syncthreads();

    // ---- ct partial over the l-slice (y from LDS) -------------------------
    {
      const int d = tid & 255, part = tid >> 8;
      float acc = 0.f;
#pragma unroll 8
      for (int i = 0; i < 32; ++i)
        acc += e_s[part * 32 + i] * y_lds[(part * 32 + i) * 256 + d];
      __syncthreads();
      red_s[tid] = acc;
    }
    __syncthreads();
    if (tid < H_)
      cstore(&ctp[(b * 8 + g) * H_ + tid], red_s[tid] + red_s[tid + 256]);
    group_barrier(cnt, ++target);

    // ---- ct finalize + merge ---------------------------------------------
    if (tid < 8) esum_s[tid] = cload(&esb[b * 8 + tid]);
    if (tid < H_) mg_s[tid] = x[(size_t)(b * L1_ + t) * H_ + tid];
    __syncthreads();
    if (tid < H_) {
      float tot = esum_s[0] + esum_s[1] + esum_s[2] + esum_s[3] + esum_s[4] +
                  esum_s[5] + esum_s[6] + esum_s[7];
      float ctv = 0.f;
#pragma unroll
      for (int g2 = 0; g2 < 8; ++g2) ctv += cload(&ctp[(b * 8 + g2) * H_ + tid]);
      mg_s[H_ + tid] = ctv * frcp(tot);
    }
    __syncthreads();

    // ---- E: li-slice [g*64, g*64+64) --------------------------------------
    {
      const int o = tid >> 3, sub = tid & 7;
      const float4* wg4 = (const float4*)(Wg + (size_t)(g * 64 + o) * 512);
      const float4* m4 = (const float4*)mg_s;
      float acc = 0.f;
#pragma unroll
      for (int j = 0; j < 16; ++j)
        acc += dot4(wg4[sub + 8 * j], m4[sub + 8 * j]);
      acc += __shfl_xor(acc, 1);
      acc += __shfl_xor(acc, 2);
      acc += __shfl_xor(acc, 4);
      if (sub == 0) {
        float gt = fsig(acc + bg[g * 64 + o]);
        cstore(&lib[b * 512 + g * 64 + o], xm ? 0.f : gt * mg_s[g * 64 + o]);
      }
    }
    group_barrier(cnt, ++target);

    // ---- F: gates for h-dims [g*32, g*32+32) ------------------------------
    li_s[tid] = cload(&lib[b * 512 + tid]);
    __syncthreads();
    {
      const int r = tid >> 2, sub = tid & 3;
      const int grow = (r >> 5) * H_ + g * 32 + (r & 31);
      const float4* wi4 = (const float4*)(Wih + (size_t)grow * 512);
      const float4* wh4 = (const float4*)(Whh + (size_t)grow * 256);
      const float4* l4 = (const float4*)li_s;
      const float4* h4 = (const float4*)h_s;
      float acc = 0.f;
#pragma unroll 8
      for (int j = 0; j < 32; ++j)
        acc += dot4(wi4[sub + 4 * j], l4[sub + 4 * j]);
#pragma unroll 8
      for (int j = 0; j < 16; ++j)
        acc += dot4(wh4[sub + 4 * j], h4[sub + 4 * j]);
      acc += __shfl_xor(acc, 1);
      acc += __shfl_xor(acc, 2);
      if (sub == 0) gate_s[r] = acc + bih[grow] + bhh[grow];
    }
    __syncthreads();
    if (tid < 32) {
      float ii = gate_s[tid], ff = gate_s[32 + tid];
      float gg = gate_s[64 + tid], oo = gate_s[96 + tid];
      float cn = fsig(ff) * c_s[tid] + fsig(ii) * ftanh(gg);
      float hn = xm ? 0.f : fsig(oo) * ftanh(cn);
      c_s[tid] = cn;
      hn_s[tid] = hn;
      cstore(&hb[b * H_ + g * 32 + tid], hn);
      out[(size_t)(b * L1_ + t) * H_ + g * 32 + tid] = hn;
    }
    __syncthreads();

    // ---- A': qpart for next step from new h slice -------------------------
    {
      const int j = tid >> 1, sub = tid & 1;
      const float4* w4 =
          (const float4*)(Wvp + (size_t)j * H_ + g * 32 + sub * 16);
      const float4* hv4 = (const float4*)(hn_s + sub * 16);
      float acc = 0.f;
#pragma unroll
      for (int i = 0; i < 4; ++i) acc += dot4(w4[i], hv4[i]);
      acc += __shfl_xor(acc, 1);
      if (sub == 0) cstore(&qp[(b * 8 + g) * H_ + j], acc);
    }
    group_barrier(cnt, ++target);
  }
}

extern "C" void kernel_launch(void* const* d_in, const int* in_sizes, int n_in,
                              void* d_out, int out_size, void* d_ws,
                              size_t ws_size, hipStream_t stream) {
  const float* x = (const float*)d_in[0];
  const int* x_mask = (const int*)d_in[1];
  const float* y = (const float*)d_in[2];
  const int* y_mask = (const int*)d_in[3];
  const float* h0 = (const float*)d_in[4];
  const float* c0 = (const float*)d_in[5];
  const float* Wq = (const float*)d_in[6];
  const float* bq = (const float*)d_in[7];
  const float* Wup = (const float*)d_in[8];
  const float* bup = (const float*)d_in[9];
  const float* Wvp = (const float*)d_in[10];
  const float* bvp = (const float*)d_in[11];
  const float* Vw = (const float*)d_in[12];
  const float* Vb = (const float*)d_in[13];
  const float* Wg = (const float*)d_in[14];
  const float* bg = (const float*)d_in[15];
  const float* Wih = (const float*)d_in[16];
  const float* Whh = (const float*)d_in[17];
  const float* bih = (const float*)d_in[18];
  const float* bhh = (const float*)d_in[19];

  float* out = (float*)d_out;
  char* ws = (char*)d_ws;

  hipMemsetAsync(ws + BAR_OFF, 0, 4096, stream);  // barrier counters -> 0
  proj_kernel<<<dim3(640), dim3(256), 0, stream>>>(
      y, Wq, bq, x, Wup, bup, (__hip_bfloat16*)(ws + YP_OFF),
      (__hip_bfloat16*)(ws + XUP_OFF));
  scan_kernel<<<dim3(B_ * GRP), dim3(TB), 0, stream>>>(
      x, x_mask, y, y_mask, h0, c0, Wvp, bvp, Vw, Vb, Wg, bg, Wih, Whh, bih,
      bhh, ws, out);
}

// Round 6
// 1655.898 us; speedup vs baseline: 13.0178x; 1.0711x over previous
//
#include <hip/hip_runtime.h>
#include <hip/hip_bf16.h>

// GatedMatchRNN: B=32, L1=128, L2=512, H=256
// Round 6: round-4 proven RMW group barrier (hardened with all-wave vmcnt
// drain) + bf16 LSTM weights (Wg/Wih/Whh via wconv) + LDS-cached biases/masks
// + LDS-resident yp/y slices. Fence-free coherent comm (no L2 invalidates).

#define B_ 32
#define L1_ 128
#define L2_ 512
#define H_ 256
#define GRP 8
#define TB 512
#define LOG2E_ 1.4426950408889634f

// ws layout (bytes)
#define YP_OFF   0u                        // bf16 [32][512][256] = 8 MB
#define XUP_OFF  (8u << 20)                // bf16 [32][128][256] = 2 MB
#define QP_OFF   (10u << 20)               // f32 [32][8][256] = 256 KB
#define CTP_OFF  (QP_OFF + (256u << 10))   // f32 [32][8][256] = 256 KB
#define ES_OFF   (CTP_OFF + (256u << 10))  // f32 [32][8] (padded 4 KB)
#define LI_OFF   (ES_OFF + (4u << 10))     // f32 [32][512] = 64 KB
#define HB_OFF   (LI_OFF + (64u << 10))    // f32 [32][256] = 32 KB
#define BAR_OFF  (HB_OFF + (32u << 10))    // uint counters [32][32] = 4 KB
#define WGB_OFF  (BAR_OFF + (4u << 10))    // bf16 Wg [512][512] = 512 KB
#define WIHB_OFF (WGB_OFF + (512u << 10))  // bf16 Wih [1024][512] = 1 MB
#define WHHB_OFF (WIHB_OFF + (1024u << 10))// bf16 Whh [1024][256] = 512 KB
// end ~12.6 MB (ws >= 16 MB, proven round 2)

__device__ __forceinline__ float fexp2(float x) {
#if __has_builtin(__builtin_amdgcn_exp2f)
  return __builtin_amdgcn_exp2f(x);
#else
  return exp2f(x);
#endif
}
__device__ __forceinline__ float frcp(float x) {
#if __has_builtin(__builtin_amdgcn_rcpf)
  return __builtin_amdgcn_rcpf(x);
#else
  return 1.0f / x;
#endif
}
__device__ __forceinline__ float ftanh(float x) {
  return 1.0f - 2.0f * frcp(1.0f + fexp2(x * (2.0f * LOG2E_)));
}
__device__ __forceinline__ float fsig(float x) {
  return frcp(1.0f + fexp2(-x * LOG2E_));
}
__device__ __forceinline__ float dot4(float4 a, float4 b) {
  return a.x * b.x + a.y * b.y + a.z * b.z + a.w * b.w;
}
__device__ __forceinline__ float bfl(unsigned u) {
  return __uint_as_float(u << 16);
}
__device__ __forceinline__ float bfh(unsigned u) {
  return __uint_as_float(u & 0xffff0000u);
}
__device__ __forceinline__ unsigned short f2bf(float f) {
  __hip_bfloat16 b = __float2bfloat16(f);
  return *reinterpret_cast<unsigned short*>(&b);
}

// Per-access device-coherent load/store (sc0 sc1). No cache invalidates.
__device__ __forceinline__ float cload(const float* p) {
  return __hip_atomic_load(p, __ATOMIC_RELAXED, __HIP_MEMORY_SCOPE_AGENT);
}
__device__ __forceinline__ void cstore(float* p, float v) {
  __hip_atomic_store(p, v, __ATOMIC_RELAXED, __HIP_MEMORY_SCOPE_AGENT);
}

// Monotonic-counter RMW barrier (round-4 proven), hardened: EVERY wave
// drains its own outstanding coherent stores (vmcnt) before the s_barrier,
// so thread 0's arrive-RMW provably follows all data-store retirements.
// RMW arrive/poll serialize at the coherence point (globally ordered).
__device__ __forceinline__ void group_barrier(unsigned* cnt, unsigned target) {
  asm volatile("s_waitcnt vmcnt(0)" ::: "memory");
  __syncthreads();
  if (threadIdx.x == 0) {
    __hip_atomic_fetch_add(cnt, 1u, __ATOMIC_RELAXED,
                           __HIP_MEMORY_SCOPE_AGENT);
    while (__hip_atomic_fetch_add(cnt, 0u, __ATOMIC_RELAXED,
                                  __HIP_MEMORY_SCOPE_AGENT) <
           GRP * target) {
    }
  }
  __syncthreads();
  asm volatile("" ::: "memory");
}

// ---------------------------------------------------------------------------
// Projection: blocks 0..511 -> yp (bf16), 512..639 -> xup (bf16).
// ---------------------------------------------------------------------------
__global__ __launch_bounds__(256) void proj_kernel(
    const float* __restrict__ y, const float* __restrict__ Wq,
    const float* __restrict__ bq, const float* __restrict__ x,
    const float* __restrict__ Wup, const float* __restrict__ bup,
    __hip_bfloat16* __restrict__ yp, __hip_bfloat16* __restrict__ xup) {
  __shared__ float As[32 * 256];
  const int blk = blockIdx.x;
  const int tid = threadIdx.x;
  const float* src;
  const float* W;
  const float* bias;
  __hip_bfloat16* dst;
  int row0;
  if (blk < 512) {
    src = y; W = Wq; bias = bq; dst = yp; row0 = blk * 32;
  } else {
    src = x; W = Wup; bias = bup; dst = xup; row0 = (blk - 512) * 32;
  }
  const float4* s4 = (const float4*)(src + (size_t)row0 * H_);
  float4* A4 = (float4*)As;
#pragma unroll
  for (int i = 0; i < 8; ++i) A4[i * 256 + tid] = s4[i * 256 + tid];
  __syncthreads();

  const float4* w4 = (const float4*)(W + (size_t)tid * H_);
  float acc[32];
#pragma unroll
  for (int r = 0; r < 32; ++r) acc[r] = 0.0f;
  for (int kc = 0; kc < 64; ++kc) {
    float4 w = w4[kc];
#pragma unroll
    for (int r = 0; r < 32; ++r) acc[r] += dot4(A4[r * 64 + kc], w);
  }
  const float bb = bias[tid];
#pragma unroll 4
  for (int r = 0; r < 32; ++r)
    dst[(size_t)(row0 + r) * H_ + tid] = __float2bfloat16(acc[r] + bb);
}

// ---------------------------------------------------------------------------
// Weight conversion: Wg(512x512), Wih(1024x512), Whh(1024x256) -> bf16 in ws.
// ---------------------------------------------------------------------------
__global__ __launch_bounds__(256) void wconv_kernel(
    const float* __restrict__ Wg, const float* __restrict__ Wih,
    const float* __restrict__ Whh, unsigned short* __restrict__ wgb,
    unsigned short* __restrict__ wihb, unsigned short* __restrict__ whhb) {
  const int e = blockIdx.x * 256 + threadIdx.x;  // float4 index
  const float* src;
  unsigned short* dst;
  int off;
  if (e < 65536) {
    src = Wg; dst = wgb; off = e;
  } else if (e < 196608) {
    src = Wih; dst = wihb; off = e - 65536;
  } else {
    src = Whh; dst = whhb; off = e - 196608;
  }
  float4 v = ((const float4*)src)[off];
  ushort4 o;
  o.x = f2bf(v.x); o.y = f2bf(v.y); o.z = f2bf(v.z); o.w = f2bf(v.w);
  ((ushort4*)dst)[off] = o;
}

// ---------------------------------------------------------------------------
// Scan: block (b,g); b = blk>>3, g = blk&7. 512 threads.
// ---------------------------------------------------------------------------
__global__ __launch_bounds__(TB) void scan_kernel(
    const float* __restrict__ x, const int* __restrict__ x_mask,
    const float* __restrict__ y, const int* __restrict__ y_mask,
    const float* __restrict__ h0, const float* __restrict__ c0,
    const float* __restrict__ Wvp, const float* __restrict__ bvp,
    const float* __restrict__ Vw, const float* __restrict__ Vb,
    const float* __restrict__ bg, const float* __restrict__ bih,
    const float* __restrict__ bhh, char* __restrict__ ws,
    float* __restrict__ out) {
  const int blk = blockIdx.x;
  const int b = blk >> 3;
  const int g = blk & 7;  // same-g blocks share an XCD (perf heuristic only)
  const int tid = threadIdx.x;

  const __hip_bfloat16* yp = (const __hip_bfloat16*)(ws + YP_OFF);
  const unsigned short* xupb = (const unsigned short*)(ws + XUP_OFF);
  float* qp = (float*)(ws + QP_OFF);
  float* ctp = (float*)(ws + CTP_OFF);
  float* esb = (float*)(ws + ES_OFF);
  float* lib = (float*)(ws + LI_OFF);
  float* hb = (float*)(ws + HB_OFF);
  unsigned* cnt = (unsigned*)(ws + BAR_OFF) + b * 32;  // 128B per batch
  const unsigned short* wgb = (const unsigned short*)(ws + WGB_OFF);
  const unsigned short* wihb = (const unsigned short*)(ws + WIHB_OFF);
  const unsigned short* whhb = (const unsigned short*)(ws + WHHB_OFF);

  __shared__ uint4 yp_lds[64 * 32];  // 32 KB, XOR-swizzled bf16 rows
  __shared__ float y_lds[64 * 256];  // 64 KB
  __shared__ __align__(16) float h_s[H_];
  __shared__ float q_s[H_];
  __shared__ float v_s[H_];
  __shared__ float bvp_s[H_];
  __shared__ float e_s[64];
  __shared__ __align__(16) float mg_s[2 * H_];
  __shared__ __align__(16) float li_s[2 * H_];
  __shared__ float gate_s[128];
  __shared__ float red_s[64 * 9];
  __shared__ float esum_s[8];
  __shared__ __align__(16) float c_s[32];
  __shared__ __align__(16) float hn_s[32];
  __shared__ float bg_s[64];
  __shared__ float bi_s[128];
  __shared__ int ym_s[64];
  __shared__ int xm_s[L1_];

  unsigned target = 0;

  // ---- stage t-invariant data ----
  {
    const uint4* src = (const uint4*)(yp + (size_t)(b * L2_ + g * 64) * H_);
    for (int k = tid; k < 64 * 32; k += TB) {
      int r = k >> 5, c = k & 31;
      yp_lds[r * 32 + (c ^ (r & 31))] = src[k];  // swizzle kills bank conflicts
    }
    const float4* ys = (const float4*)(y + (size_t)(b * L2_ + g * 64) * H_);
    float4* yd = (float4*)y_lds;
    for (int k = tid; k < 64 * 64; k += TB) yd[k] = ys[k];
  }
  if (tid < H_) {
    v_s[tid] = Vw[tid];
    bvp_s[tid] = bvp[tid];
  }
  if (tid < 64) {
    ym_s[tid] = y_mask[b * L2_ + g * 64 + tid];
    bg_s[tid] = bg[g * 64 + tid];
  }
  if (tid < 128) {
    xm_s[tid] = x_mask[b * L1_ + tid];
    const int grow = (tid >> 5) * H_ + g * 32 + (tid & 31);
    bi_s[tid] = bih[grow] + bhh[grow];
  }
  if (tid < 32) {
    float hv = h0[b * H_ + g * 32 + tid];
    c_s[tid] = c0[b * H_ + g * 32 + tid];
    hn_s[tid] = hv;
    cstore(&hb[b * H_ + g * 32 + tid], hv);
  }
  const float vb = Vb[0];
  __syncthreads();
  {  // initial qpart from h0 slice (column-split of Wvp, f32)
    const int j = tid >> 1, sub = tid & 1;
    const float4* w4 =
        (const float4*)(Wvp + (size_t)j * H_ + g * 32 + sub * 16);
    const float4* hv4 = (const float4*)(hn_s + sub * 16);
    float acc = 0.f;
#pragma unroll
    for (int i = 0; i < 4; ++i) acc += dot4(w4[i], hv4[i]);
    acc += __shfl_xor(acc, 1);
    if (sub == 0) cstore(&qp[(b * 8 + g) * H_ + j], acc);
  }
  group_barrier(cnt, ++target);

  for (int t = 0; t < L1_; ++t) {
    const int xm = xm_s[t];

    // ---- q finalize + load prev h (coherent reads) ------------------------
    if (tid < H_) {
      h_s[tid] = cload(&hb[b * H_ + tid]);
      float acc = bvp_s[tid] + bfl(xupb[(size_t)(b * L1_ + t) * H_ + tid]);
#pragma unroll
      for (int g2 = 0; g2 < 8; ++g2) acc += cload(&qp[(b * 8 + g2) * H_ + tid]);
      q_s[tid] = acc;
    }
    __syncthreads();

    // ---- B: scores for l-slice [g*64, g*64+64), yp from swizzled LDS ------
    {
      const int l = tid & 63, sub = tid >> 6;
      float acc = 0.f;
#pragma unroll
      for (int i = 0; i < 4; ++i) {
        uint4 u = yp_lds[l * 32 + ((sub * 4 + i) ^ (l & 31))];
        const int h = sub * 32 + i * 8;
        acc += v_s[h + 0] * ftanh(q_s[h + 0] + bfl(u.x));
        acc += v_s[h + 1] * ftanh(q_s[h + 1] + bfh(u.x));
        acc += v_s[h + 2] * ftanh(q_s[h + 2] + bfl(u.y));
        acc += v_s[h + 3] * ftanh(q_s[h + 3] + bfh(u.y));
        acc += v_s[h + 4] * ftanh(q_s[h + 4] + bfl(u.z));
        acc += v_s[h + 5] * ftanh(q_s[h + 5] + bfh(u.z));
        acc += v_s[h + 6] * ftanh(q_s[h + 6] + bfl(u.w));
        acc += v_s[h + 7] * ftanh(q_s[h + 7] + bfh(u.w));
      }
      red_s[l * 9 + sub] = acc;  // stride 9 (2-way max, free)
    }
    __syncthreads();
    if (tid < 64) {
      float s = vb;
#pragma unroll
      for (int k = 0; k < 8; ++k) s += red_s[tid * 9 + k];
      // |s| <= |Vb| + sum|v| ~ 13 -> exp never overflows; no global max
      float e = ym_s[tid] ? 0.f : fexp2(s * LOG2E_);
      e_s[tid] = e;
      float ss = e;
#pragma unroll
      for (int off = 32; off >= 1; off >>= 1) ss += __shfl_xor(ss, off);
      if (tid == 0) cstore(&esb[b * 8 + g], ss);
    }
    __syncthreads();

    // ---- ct partial over the l-slice (y from LDS) -------------------------
    {
      const int d = tid & 255, part = tid >> 8;
      float acc = 0.f;
#pragma unroll 8
      for (int i = 0; i < 32; ++i)
        acc += e_s[part * 32 + i] * y_lds[(part * 32 + i) * 256 + d];
      __syncthreads();
      red_s[tid] = acc;
    }
    __syncthreads();
    if (tid < H_)
      cstore(&ctp[(b * 8 + g) * H_ + tid], red_s[tid] + red_s[tid + 256]);
    group_barrier(cnt, ++target);

    // ---- ct finalize + merge ---------------------------------------------
    if (tid < 8) esum_s[tid] = cload(&esb[b * 8 + tid]);
    if (tid < H_) mg_s[tid] = x[(size_t)(b * L1_ + t) * H_ + tid];
    __syncthreads();
    if (tid < H_) {
      float tot = esum_s[0] + esum_s[1] + esum_s[2] + esum_s[3] + esum_s[4] +
                  esum_s[5] + esum_s[6] + esum_s[7];
      float ctv = 0.f;
#pragma unroll
      for (int g2 = 0; g2 < 8; ++g2)
        ctv += cload(&ctp[(b * 8 + g2) * H_ + tid]);
      mg_s[H_ + tid] = ctv * frcp(tot);
    }
    __syncthreads();

    // ---- E: li-slice [g*64, g*64+64), Wg in bf16 --------------------------
    {
      const int o = tid >> 3, sub = tid & 7;
      const uint4* wrow = (const uint4*)(wgb + (size_t)(g * 64 + o) * 512);
      const float4* m4 = (const float4*)mg_s;
      float acc = 0.f;
#pragma unroll
      for (int j = 0; j < 8; ++j) {
        uint4 u = wrow[sub + 8 * j];
        float4 ma = m4[(sub + 8 * j) * 2], mb = m4[(sub + 8 * j) * 2 + 1];
        acc += bfl(u.x) * ma.x + bfh(u.x) * ma.y + bfl(u.y) * ma.z +
               bfh(u.y) * ma.w + bfl(u.z) * mb.x + bfh(u.z) * mb.y +
               bfl(u.w) * mb.z + bfh(u.w) * mb.w;
      }
      acc += __shfl_xor(acc, 1);
      acc += __shfl_xor(acc, 2);
      acc += __shfl_xor(acc, 4);
      if (sub == 0) {
        float gt = fsig(acc + bg_s[o]);
        cstore(&lib[b * 512 + g * 64 + o], xm ? 0.f : gt * mg_s[g * 64 + o]);
      }
    }
    group_barrier(cnt, ++target);

    // ---- F: gates for h-dims [g*32, g*32+32), Wih/Whh in bf16 -------------
    li_s[tid] = cload(&lib[b * 512 + tid]);
    __syncthreads();
    {
      const int r = tid >> 2, sub = tid & 3;
      const int grow = (r >> 5) * H_ + g * 32 + (r & 31);
      const uint4* wi = (const uint4*)(wihb + (size_t)grow * 512);
      const uint4* wh = (const uint4*)(whhb + (size_t)grow * 256);
      const float4* l4 = (const float4*)li_s;
      const float4* h4 = (const float4*)h_s;
      float acc = 0.f;
#pragma unroll
      for (int j = 0; j < 16; ++j) {
        uint4 u = wi[sub + 4 * j];
        float4 a = l4[(sub + 4 * j) * 2], c2 = l4[(sub + 4 * j) * 2 + 1];
        acc += bfl(u.x) * a.x + bfh(u.x) * a.y + bfl(u.y) * a.z +
               bfh(u.y) * a.w + bfl(u.z) * c2.x + bfh(u.z) * c2.y +
               bfl(u.w) * c2.z + bfh(u.w) * c2.w;
      }
#pragma unroll
      for (int j = 0; j < 8; ++j) {
        uint4 u = wh[sub + 4 * j];
        float4 a = h4[(sub + 4 * j) * 2], c2 = h4[(sub + 4 * j) * 2 + 1];
        acc += bfl(u.x) * a.x + bfh(u.x) * a.y + bfl(u.y) * a.z +
               bfh(u.y) * a.w + bfl(u.z) * c2.x + bfh(u.z) * c2.y +
               bfl(u.w) * c2.z + bfh(u.w) * c2.w;
      }
      acc += __shfl_xor(acc, 1);
      acc += __shfl_xor(acc, 2);
      if (sub == 0) gate_s[r] = acc + bi_s[r];
    }
    __syncthreads();
    if (tid < 32) {
      float ii = gate_s[tid], ff = gate_s[32 + tid];
      float gg = gate_s[64 + tid], oo = gate_s[96 + tid];
      float cn = fsig(ff) * c_s[tid] + fsig(ii) * ftanh(gg);
      float hn = xm ? 0.f : fsig(oo) * ftanh(cn);
      c_s[tid] = cn;
      hn_s[tid] = hn;
      cstore(&hb[b * H_ + g * 32 + tid], hn);
      out[(size_t)(b * L1_ + t) * H_ + g * 32 + tid] = hn;
    }
    __syncthreads();

    // ---- A': qpart for next step from new h slice (Wvp f32) ---------------
    {
      const int j = tid >> 1, sub = tid & 1;
      const float4* w4 =
          (const float4*)(Wvp + (size_t)j * H_ + g * 32 + sub * 16);
      const float4* hv4 = (const float4*)(hn_s + sub * 16);
      float acc = 0.f;
#pragma unroll
      for (int i = 0; i < 4; ++i) acc += dot4(w4[i], hv4[i]);
      acc += __shfl_xor(acc, 1);
      if (sub == 0) cstore(&qp[(b * 8 + g) * H_ + j], acc);
    }
    group_barrier(cnt, ++target);
  }
}

extern "C" void kernel_launch(void* const* d_in, const int* in_sizes, int n_in,
                              void* d_out, int out_size, void* d_ws,
                              size_t ws_size, hipStream_t stream) {
  const float* x = (const float*)d_in[0];
  const int* x_mask = (const int*)d_in[1];
  const float* y = (const float*)d_in[2];
  const int* y_mask = (const int*)d_in[3];
  const float* h0 = (const float*)d_in[4];
  const float* c0 = (const float*)d_in[5];
  const float* Wq = (const float*)d_in[6];
  const float* bq = (const float*)d_in[7];
  const float* Wup = (const float*)d_in[8];
  const float* bup = (const float*)d_in[9];
  const float* Wvp = (const float*)d_in[10];
  const float* bvp = (const float*)d_in[11];
  const float* Vw = (const float*)d_in[12];
  const float* Vb = (const float*)d_in[13];
  const float* Wg = (const float*)d_in[14];
  const float* bg = (const float*)d_in[15];
  const float* Wih = (const float*)d_in[16];
  const float* Whh = (const float*)d_in[17];
  const float* bih = (const float*)d_in[18];
  const float* bhh = (const float*)d_in[19];

  float* out = (float*)d_out;
  char* ws = (char*)d_ws;

  hipMemsetAsync(ws + BAR_OFF, 0, 4096, stream);  // barrier counters -> 0
  proj_kernel<<<dim3(640), dim3(256), 0, stream>>>(
      y, Wq, bq, x, Wup, bup, (__hip_bfloat16*)(ws + YP_OFF),
      (__hip_bfloat16*)(ws + XUP_OFF));
  wconv_kernel<<<dim3(1024), dim3(256), 0, stream>>>(
      Wg, Wih, Whh, (unsigned short*)(ws + WGB_OFF),
      (unsigned short*)(ws + WIHB_OFF), (unsigned short*)(ws + WHHB_OFF));
  scan_kernel<<<dim3(B_ * GRP), dim3(TB), 0, stream>>>(
      x, x_mask, y, y_mask, h0, c0, Wvp, bvp, Vw, Vb, bg, bih, bhh, ws, out);
}